// Round 7
// baseline (422.586 us; speedup 1.0000x reference)
//
#include <hip/hip_runtime.h>

#define NN 2048
#define KK 512

typedef __attribute__((ext_vector_type(8))) short bf16x8;
typedef __attribute__((ext_vector_type(4))) float f32x4;

__device__ inline ushort f2bf(float x) {  // RNE f32->bf16
  union { float f; unsigned u; } v; v.f = x;
  unsigned r = v.u + 0x7fffu + ((v.u >> 16) & 1u);
  return (ushort)(r >> 16);
}

// -------- K0: W -> WT_hi/WT_lo (bf16 split, [n][k]) + zero cnt. grid 32 ----
__global__ __launch_bounds__(256) void k_wprep(
    const float* __restrict__ W, ushort* __restrict__ wthi,
    ushort* __restrict__ wtlo, int* __restrict__ cnt) {
  if (blockIdx.x == 0 && threadIdx.x < 128) cnt[threadIdx.x] = 0;
  __shared__ float ts[64][65];
  const int t = threadIdx.x;
  const int kb = (blockIdx.x >> 2) * 64;
  const int nb = (blockIdx.x & 3) * 64;
  const int r = t >> 6, c = t & 63;
#pragma unroll
  for (int p = 0; p < 16; ++p)
    ts[p * 4 + r][c] = W[(size_t)(kb + p * 4 + r) * 256 + nb + c];
  __syncthreads();
#pragma unroll
  for (int p = 0; p < 16; ++p) {
    int n = p * 4 + r;
    int k = c;
    float v = ts[k][n];
    union { float f; unsigned u; } q; q.f = v;
    ushort hi = (ushort)(q.u >> 16);
    union { float f; unsigned u; } hf; hf.u = q.u & 0xffff0000u;
    ushort lo = f2bf(v - hf.f);
    size_t off = (size_t)(nb + n) * KK + kb + k;
    wthi[off] = hi;
    wtlo[off] = lo;
  }
}

// -------- K1: g = h@W via split-bf16 MFMA; writes gTb + all exp tables -----
// grid 128 (16 rows each), block 256 (wave = head)
__global__ __launch_bounds__(256) void k_gemm(
    const float* __restrict__ hin, const ushort* __restrict__ wthi,
    const ushort* __restrict__ wtlo, const float* __restrict__ aw,
    ushort* __restrict__ gTb,
    float* __restrict__ Eel, float* __restrict__ Fel,
    float* __restrict__ Eer_jh, float* __restrict__ Fer_jh,
    float* __restrict__ Eer_hj, float* __restrict__ Fer_hj) {
  __shared__ float hs[16][516];
  const int tid = threadIdx.x;
  const int i0 = blockIdx.x * 16;
#pragma unroll
  for (int p = 0; p < 8; ++p) {
    int g4 = tid + p * 256;
    int row = g4 >> 7, col = (g4 & 127) << 2;
    *(float4*)&hs[row][col] = *(const float4*)(hin + (size_t)(i0 + row) * KK + col);
  }
  __syncthreads();

  const int h = tid >> 6;
  const int lane = tid & 63;
  const int il = lane & 15;
  const int kg = lane >> 4;

  f32x4 acc[4];
#pragma unroll
  for (int nt = 0; nt < 4; ++nt) acc[nt] = (f32x4){0.f, 0.f, 0.f, 0.f};

  const ushort* bh_base = wthi + (size_t)(h * 64 + il) * KK;
  const ushort* bl_base = wtlo + (size_t)(h * 64 + il) * KK;

#pragma unroll 4
  for (int ks = 0; ks < 16; ++ks) {
    const int ko = ks * 32 + kg * 8;
    float4 a01 = *(const float4*)&hs[il][ko];
    float4 a23 = *(const float4*)&hs[il][ko + 4];
    float av[8] = {a01.x, a01.y, a01.z, a01.w, a23.x, a23.y, a23.z, a23.w};
    union { unsigned u[4]; bf16x8 v; } Ah, Al;
#pragma unroll
    for (int p = 0; p < 4; ++p) {
      union { float f; unsigned u; } u0, u1;
      u0.f = av[2 * p]; u1.f = av[2 * p + 1];
      Ah.u[p] = (u0.u >> 16) | (u1.u & 0xffff0000u);
      union { float f; unsigned u; } h0, h1;
      h0.u = u0.u & 0xffff0000u;
      h1.u = u1.u & 0xffff0000u;
      union { float f; unsigned u; } r0, r1;
      r0.f = av[2 * p] - h0.f;
      r1.f = av[2 * p + 1] - h1.f;
      Al.u[p] = (r0.u >> 16) | (r1.u & 0xffff0000u);
    }
#pragma unroll
    for (int nt = 0; nt < 4; ++nt) {
      bf16x8 Bh = *(const bf16x8*)(bh_base + nt * 16 * KK + ko);
      bf16x8 Bl = *(const bf16x8*)(bl_base + nt * 16 * KK + ko);
      acc[nt] = __builtin_amdgcn_mfma_f32_16x16x32_bf16(Ah.v, Bh, acc[nt], 0, 0, 0);
      acc[nt] = __builtin_amdgcn_mfma_f32_16x16x32_bf16(Al.v, Bh, acc[nt], 0, 0, 0);
      acc[nt] = __builtin_amdgcn_mfma_f32_16x16x32_bf16(Ah.v, Bl, acc[nt], 0, 0, 0);
    }
  }

  // gTb write: layout [j/8][f][8] bf16, C/D: col(il)=n=f, row(kg*4+q)=i=j
  const int jb = (i0 >> 3) + (kg >> 1);
  const int halfoff = (kg & 1) * 4;
#pragma unroll
  for (int nt = 0; nt < 4; ++nt) {
    const int f = h * 64 + nt * 16 + il;
    unsigned w0 = (unsigned)f2bf(acc[nt][0]) | ((unsigned)f2bf(acc[nt][1]) << 16);
    unsigned w1 = (unsigned)f2bf(acc[nt][2]) | ((unsigned)f2bf(acc[nt][3]) << 16);
    uint2 pk = make_uint2(w0, w1);
    *(uint2*)(gTb + (size_t)jb * 2048 + f * 8 + halfoff) = pk;
  }

  // el/er epilogue -> exp tables directly
  float ela[4] = {0.f, 0.f, 0.f, 0.f}, era[4] = {0.f, 0.f, 0.f, 0.f};
#pragma unroll
  for (int nt = 0; nt < 4; ++nt) {
    float as = aw[nt * 16 + il];
    float ad = aw[64 + nt * 16 + il];
#pragma unroll
    for (int q = 0; q < 4; ++q) {
      ela[q] += acc[nt][q] * as;
      era[q] += acc[nt][q] * ad;
    }
  }
#pragma unroll
  for (int m = 1; m < 16; m <<= 1) {
#pragma unroll
    for (int q = 0; q < 4; ++q) {
      ela[q] += __shfl_xor(ela[q], m);
      era[q] += __shfl_xor(era[q], m);
    }
  }
  if (il == 0) {
#pragma unroll
    for (int q = 0; q < 4; ++q) {
      const int row = i0 + kg * 4 + q;
      float eel = __expf(ela[q]);
      float fel = __expf(0.2f * ela[q]);
      float eer = __expf(era[q]);
      float fer = __expf(0.2f * era[q]);
      Eel[row * 4 + h] = eel;
      Fel[row * 4 + h] = fel;
      Eer_jh[row * 4 + h] = eer;
      Fer_jh[row * 4 + h] = fer;
      Eer_hj[h * NN + row] = eer;
      Fer_hj[h * NN + row] = fer;
    }
  }
}

// -------- K3: Z1[h], Z2 + adjacency bitmask. grid 2048 (block = row) -------
__global__ __launch_bounds__(256) void k_rowz(
    const float* __restrict__ adj, const float* __restrict__ s,
    const float* __restrict__ Eel, const float* __restrict__ Fel,
    const float* __restrict__ Eer_jh, const float* __restrict__ Fer_jh,
    float* __restrict__ rZ1, float* __restrict__ rZ2,
    unsigned long long* __restrict__ maskb) {
  const int row = blockIdx.x;
  const int tid = threadIdx.x;
  const int wq = tid >> 6;
  const int lane = tid & 63;

  float4 e4 = *(const float4*)(Eel + row * 4);
  float4 f4 = *(const float4*)(Fel + row * 4);
  const float eel[4] = {e4.x, e4.y, e4.z, e4.w};
  const float fel[4] = {f4.x, f4.y, f4.z, f4.w};

  float z1[4] = {0.f, 0.f, 0.f, 0.f};
  float z2 = 0.f;

  const float* ap = adj + (size_t)row * NN + wq * 512;
  const float* sp = s + (size_t)row * NN + wq * 512;

#pragma unroll
  for (int it = 0; it < 8; ++it) {
    const int j = it * 64 + lane;
    float a = ap[j];
    float sv = sp[j];
    bool nb = (a != 0.f);
    unsigned long long m = __ballot(nb);
    if (lane == 0) maskb[row * 32 + wq * 8 + it] = m;
    const int jg = wq * 512 + j;
    float4 eer4 = *(const float4*)(Eer_jh + jg * 4);
    float4 fer4 = *(const float4*)(Fer_jh + jg * 4);
    z2 += nb ? __expf(sv) : 0.f;
    float ev[4] = {eer4.x, eer4.y, eer4.z, eer4.w};
    float fv[4] = {fer4.x, fer4.y, fer4.z, fer4.w};
#pragma unroll
    for (int h = 0; h < 4; ++h) {
      float p = eel[h] * ev[h];
      float q = fel[h] * fv[h];
      float E = fmaxf(p, q);  // == (p>1 ? p : q), exp monotone
      z1[h] += nb ? E : 0.f;
    }
  }

#pragma unroll
  for (int m = 1; m < 64; m <<= 1) {
    z2 += __shfl_xor(z2, m);
#pragma unroll
    for (int h = 0; h < 4; ++h) z1[h] += __shfl_xor(z1[h], m);
  }

  __shared__ float wr[4][5];
  if (lane == 0) {
    wr[wq][0] = z1[0]; wr[wq][1] = z1[1]; wr[wq][2] = z1[2]; wr[wq][3] = z1[3];
    wr[wq][4] = z2;
  }
  __syncthreads();
  if (tid < 5) {
    float sum = wr[0][tid] + wr[1][tid] + wr[2][tid] + wr[3][tid];
    if (tid < 4) rZ1[row * 4 + tid] = 1.f / sum;
    else rZ2[row] = 1.f / sum;
  }
}

// -------- K4: coefficient + MFMA contraction + fused finalize. grid 2048 ---
// wave = head h; lane: il = lane&15 (i-row), kg = lane>>4 (k-group)
__global__ __launch_bounds__(256, 6) void k_attn(
    const float* __restrict__ s, const unsigned long long* __restrict__ maskb,
    const ushort* __restrict__ gTb,
    const float* __restrict__ Eel, const float* __restrict__ Fel,
    const float* __restrict__ Eer_hj, const float* __restrict__ Fer_hj,
    const float* __restrict__ rZ1, const float* __restrict__ rZ2,
    _Float16* __restrict__ U, float* __restrict__ Z3p,
    int* __restrict__ cnt, float* __restrict__ out) {
  const int tid = threadIdx.x;
  const int h = tid >> 6;
  const int lane = tid & 63;
  const int il = lane & 15;
  const int kg = lane >> 4;
  const int ib = blockIdx.x >> 4;
  const int jc = blockIdx.x & 15;
  const int i0 = ib * 16;
  const int jb0 = jc * 128;
  const int row = i0 + il;

  const float eel = Eel[row * 4 + h];
  const float fel = Fel[row * 4 + h];
  const float rz1 = rZ1[row * 4 + h];
  const float rz2 = rZ2[row];

  const unsigned long long* mp = maskb + row * 32 + jc * 2;
  const unsigned long long m0 = mp[0];
  const unsigned long long m1 = mp[1];

  f32x4 acc[4];
#pragma unroll
  for (int nt = 0; nt < 4; ++nt) acc[nt] = (f32x4){0.f, 0.f, 0.f, 0.f};
  float z3 = 0.f;

  const float* sp = s + (size_t)row * NN + jb0 + kg * 8;
  const float* eerp = Eer_hj + h * NN + jb0 + kg * 8;
  const float* ferp = Fer_hj + h * NN + jb0 + kg * 8;
  const ushort* bp = gTb + (size_t)(jc * 16 + kg) * 2048 + (h * 64 + il) * 8;

#pragma unroll
  for (int ks = 0; ks < 4; ++ks) {
    const int o = ks * 32;
    unsigned long long w = (ks & 2) ? m1 : m0;
    unsigned byte_ = (unsigned)(w >> ((ks & 1) * 32 + kg * 8)) & 0xffu;

    bf16x8 A;
#pragma unroll
    for (int gp = 0; gp < 2; ++gp) {
      float4 s4 = *(const float4*)(sp + o + gp * 4);
      float4 ee4 = *(const float4*)(eerp + o + gp * 4);
      float4 fe4 = *(const float4*)(ferp + o + gp * 4);
      float sv[4] = {s4.x, s4.y, s4.z, s4.w};
      float ev[4] = {ee4.x, ee4.y, ee4.z, ee4.w};
      float fv[4] = {fe4.x, fe4.y, fe4.z, fe4.w};
#pragma unroll
      for (int e = 0; e < 4; ++e) {
        bool nb = (byte_ >> (gp * 4 + e)) & 1u;
        float spv = __expf(sv[e]) * rz2;
        float p = eel * ev[e];
        float q = fel * fv[e];
        float E = fmaxf(p, q);  // == (p>1 ? p : q)
        float tt = nb ? (E * rz1 + spv) : 0.f;
        float c = __expf(tt);
        z3 += c;
        A[gp * 4 + e] = (short)f2bf(c);
      }
    }

    const ushort* bks = bp + (size_t)(ks * 4) * 2048;
    acc[0] = __builtin_amdgcn_mfma_f32_16x16x32_bf16(A, *(const bf16x8*)(bks), acc[0], 0, 0, 0);
    acc[1] = __builtin_amdgcn_mfma_f32_16x16x32_bf16(A, *(const bf16x8*)(bks + 128), acc[1], 0, 0, 0);
    acc[2] = __builtin_amdgcn_mfma_f32_16x16x32_bf16(A, *(const bf16x8*)(bks + 256), acc[2], 0, 0, 0);
    acc[3] = __builtin_amdgcn_mfma_f32_16x16x32_bf16(A, *(const bf16x8*)(bks + 384), acc[3], 0, 0, 0);
  }

  z3 += __shfl_xor(z3, 16);
  z3 += __shfl_xor(z3, 32);
  if (lane < 16)
    Z3p[jc * (NN * 4) + (i0 + lane) * 4 + h] = z3;

  _Float16* up = U + (size_t)jc * (NN * 256) + (size_t)i0 * 256 + h * 64 + il;
#pragma unroll
  for (int nt = 0; nt < 4; ++nt)
#pragma unroll
    for (int q = 0; q < 4; ++q)
      up[(size_t)(kg * 4 + q) * 256 + nt * 16] = (_Float16)acc[nt][q];

  // ---- fused finalize: last of the 16 jc-sibling blocks reduces ----
  __threadfence();
  __syncthreads();
  __shared__ int is_last;
  if (tid == 0) {
    int old = atomicAdd(&cnt[ib], 1);
    is_last = (old == 15) ? 1 : 0;
  }
  __syncthreads();
  if (is_last) {
    __threadfence();  // acquire: other blocks' U/Z3p writes visible
    const int c = tid;
    const int hh = c >> 6;
    for (int r = 0; r < 16; ++r) {
      const int rowi = i0 + r;
      float u = 0.f, z = 0.f;
#pragma unroll
      for (int p = 0; p < 16; ++p) {
        u += (float)U[(size_t)p * (NN * 256) + (size_t)rowi * 256 + c];
        z += Z3p[p * (NN * 4) + rowi * 4 + hh];
      }
      out[(size_t)rowi * 256 + c] = u / z;
    }
  }
}

extern "C" void kernel_launch(void* const* d_in, const int* in_sizes, int n_in,
                              void* d_out, int out_size, void* d_ws, size_t ws_size,
                              hipStream_t stream) {
  const float* hin = (const float*)d_in[0];
  const float* adj = (const float*)d_in[1];
  const float* s = (const float*)d_in[2];
  const float* W = (const float*)d_in[3];
  const float* aw = (const float*)d_in[4];
  float* out = (float*)d_out;

  // Workspace layout (f32 slots) — audited, non-overlapping:
  //  Eel     [      0,    8192)
  //  Fel     [   8192,   16384)
  //  Eer_jh  [  16384,   24576)
  //  Fer_jh  [  24576,   32768)
  //  Eer_hj  [  32768,   40960)
  //  Fer_hj  [  40960,   49152)
  //  rZ1     [  49152,   57344)
  //  rZ2     [  57344,   59392)
  //  cnt     [  59392,   59520)   128 ints
  //  Z3p     [  59520,  190592)   16 * 8192
  //  maskb   [ 190592,  321664)   65536 u64 = 131072 slots (8B-aligned: 190592*4 % 8 == 0)
  //  wthi    [ 321664,  387200)   131072 ushort
  //  wtlo    [ 387200,  452736)   131072 ushort
  //  gTb     [ 452736,  714880)   524288 ushort
  //  U       [ 714880, 4909184)   16*2048*256 f16
  float* ws = (float*)d_ws;
  float* Eel    = ws;
  float* Fel    = ws + 8192;
  float* Eer_jh = ws + 16384;
  float* Fer_jh = ws + 24576;
  float* Eer_hj = ws + 32768;
  float* Fer_hj = ws + 40960;
  float* rZ1    = ws + 49152;
  float* rZ2    = ws + 57344;
  int*   cnt    = (int*)(ws + 59392);
  float* Z3p    = ws + 59520;
  unsigned long long* maskb = (unsigned long long*)(ws + 190592);
  ushort* wthi  = (ushort*)(ws + 321664);
  ushort* wtlo  = (ushort*)(ws + 387200);
  ushort* gTb   = (ushort*)(ws + 452736);
  _Float16* U   = (_Float16*)(ws + 714880);

  k_wprep<<<32, 256, 0, stream>>>(W, wthi, wtlo, cnt);
  k_gemm<<<128, 256, 0, stream>>>(hin, wthi, wtlo, aw, gTb, Eel, Fel, Eer_jh, Fer_jh, Eer_hj, Fer_hj);
  k_rowz<<<2048, 256, 0, stream>>>(adj, s, Eel, Fel, Eer_jh, Fer_jh, rZ1, rZ2, maskb);
  k_attn<<<2048, 256, 0, stream>>>(s, maskb, gTb, Eel, Fel, Eer_hj, Fer_hj, rZ1, rZ2, U, Z3p, cnt, out);
}

// Round 8
// 92.488 us; speedup vs baseline: 4.5691x; 4.5691x over previous
//
#include <hip/hip_runtime.h>

#define NN 2048
#define KK 512

typedef __attribute__((ext_vector_type(8))) short bf16x8;
typedef __attribute__((ext_vector_type(4))) float f32x4;

__device__ inline ushort f2bf(float x) {  // RNE f32->bf16
  union { float f; unsigned u; } v; v.f = x;
  unsigned r = v.u + 0x7fffu + ((v.u >> 16) & 1u);
  return (ushort)(r >> 16);
}

// -------- K0: W -> WT_hi/WT_lo (bf16 split, [n][k] layout). grid 32 --------
__global__ __launch_bounds__(256) void k_wprep(
    const float* __restrict__ W, ushort* __restrict__ wthi,
    ushort* __restrict__ wtlo) {
  __shared__ float ts[64][65];
  const int t = threadIdx.x;
  const int kb = (blockIdx.x >> 2) * 64;
  const int nb = (blockIdx.x & 3) * 64;
  const int r = t >> 6, c = t & 63;
#pragma unroll
  for (int p = 0; p < 16; ++p)
    ts[p * 4 + r][c] = W[(size_t)(kb + p * 4 + r) * 256 + nb + c];
  __syncthreads();
#pragma unroll
  for (int p = 0; p < 16; ++p) {
    int n = p * 4 + r;
    int k = c;
    float v = ts[k][n];
    union { float f; unsigned u; } q; q.f = v;
    ushort hi = (ushort)(q.u >> 16);
    union { float f; unsigned u; } hf; hf.u = q.u & 0xffff0000u;
    ushort lo = f2bf(v - hf.f);
    size_t off = (size_t)(nb + n) * KK + kb + k;
    wthi[off] = hi;
    wtlo[off] = lo;
  }
}

// -------- K1: g = h@W via split-bf16 MFMA; writes gTb + exp tables ---------
// grid 128 (16 rows each), block 256 (wave = head). Proven in R6/R7.
__global__ __launch_bounds__(256) void k_gemm(
    const float* __restrict__ hin, const ushort* __restrict__ wthi,
    const ushort* __restrict__ wtlo, const float* __restrict__ aw,
    ushort* __restrict__ gTb,
    float* __restrict__ Eel, float* __restrict__ Fel,
    float* __restrict__ Eer_jh, float* __restrict__ Fer_jh,
    float* __restrict__ Eer_hj, float* __restrict__ Fer_hj) {
  __shared__ float hs[16][516];
  const int tid = threadIdx.x;
  const int i0 = blockIdx.x * 16;
#pragma unroll
  for (int p = 0; p < 8; ++p) {
    int g4 = tid + p * 256;
    int row = g4 >> 7, col = (g4 & 127) << 2;
    *(float4*)&hs[row][col] = *(const float4*)(hin + (size_t)(i0 + row) * KK + col);
  }
  __syncthreads();

  const int h = tid >> 6;
  const int lane = tid & 63;
  const int il = lane & 15;
  const int kg = lane >> 4;

  f32x4 acc[4];
#pragma unroll
  for (int nt = 0; nt < 4; ++nt) acc[nt] = (f32x4){0.f, 0.f, 0.f, 0.f};

  const ushort* bh_base = wthi + (size_t)(h * 64 + il) * KK;
  const ushort* bl_base = wtlo + (size_t)(h * 64 + il) * KK;

#pragma unroll 4
  for (int ks = 0; ks < 16; ++ks) {
    const int ko = ks * 32 + kg * 8;
    float4 a01 = *(const float4*)&hs[il][ko];
    float4 a23 = *(const float4*)&hs[il][ko + 4];
    float av[8] = {a01.x, a01.y, a01.z, a01.w, a23.x, a23.y, a23.z, a23.w};
    union { unsigned u[4]; bf16x8 v; } Ah, Al;
#pragma unroll
    for (int p = 0; p < 4; ++p) {
      union { float f; unsigned u; } u0, u1;
      u0.f = av[2 * p]; u1.f = av[2 * p + 1];
      Ah.u[p] = (u0.u >> 16) | (u1.u & 0xffff0000u);
      union { float f; unsigned u; } h0, h1;
      h0.u = u0.u & 0xffff0000u;
      h1.u = u1.u & 0xffff0000u;
      union { float f; unsigned u; } r0, r1;
      r0.f = av[2 * p] - h0.f;
      r1.f = av[2 * p + 1] - h1.f;
      Al.u[p] = (r0.u >> 16) | (r1.u & 0xffff0000u);
    }
#pragma unroll
    for (int nt = 0; nt < 4; ++nt) {
      bf16x8 Bh = *(const bf16x8*)(bh_base + nt * 16 * KK + ko);
      bf16x8 Bl = *(const bf16x8*)(bl_base + nt * 16 * KK + ko);
      acc[nt] = __builtin_amdgcn_mfma_f32_16x16x32_bf16(Ah.v, Bh, acc[nt], 0, 0, 0);
      acc[nt] = __builtin_amdgcn_mfma_f32_16x16x32_bf16(Al.v, Bh, acc[nt], 0, 0, 0);
      acc[nt] = __builtin_amdgcn_mfma_f32_16x16x32_bf16(Ah.v, Bl, acc[nt], 0, 0, 0);
    }
  }

  // gTb write: layout [j/8][f][8] bf16
  const int jb = (i0 >> 3) + (kg >> 1);
  const int halfoff = (kg & 1) * 4;
#pragma unroll
  for (int nt = 0; nt < 4; ++nt) {
    const int f = h * 64 + nt * 16 + il;
    unsigned w0 = (unsigned)f2bf(acc[nt][0]) | ((unsigned)f2bf(acc[nt][1]) << 16);
    unsigned w1 = (unsigned)f2bf(acc[nt][2]) | ((unsigned)f2bf(acc[nt][3]) << 16);
    uint2 pk = make_uint2(w0, w1);
    *(uint2*)(gTb + (size_t)jb * 2048 + f * 8 + halfoff) = pk;
  }

  // el/er epilogue -> exp tables directly
  float ela[4] = {0.f, 0.f, 0.f, 0.f}, era[4] = {0.f, 0.f, 0.f, 0.f};
#pragma unroll
  for (int nt = 0; nt < 4; ++nt) {
    float as = aw[nt * 16 + il];
    float ad = aw[64 + nt * 16 + il];
#pragma unroll
    for (int q = 0; q < 4; ++q) {
      ela[q] += acc[nt][q] * as;
      era[q] += acc[nt][q] * ad;
    }
  }
#pragma unroll
  for (int m = 1; m < 16; m <<= 1) {
#pragma unroll
    for (int q = 0; q < 4; ++q) {
      ela[q] += __shfl_xor(ela[q], m);
      era[q] += __shfl_xor(era[q], m);
    }
  }
  if (il == 0) {
#pragma unroll
    for (int q = 0; q < 4; ++q) {
      const int row = i0 + kg * 4 + q;
      float eel = __expf(ela[q]);
      float fel = __expf(0.2f * ela[q]);
      float eer = __expf(era[q]);
      float fer = __expf(0.2f * era[q]);
      Eel[row * 4 + h] = eel;
      Fel[row * 4 + h] = fel;
      Eer_jh[row * 4 + h] = eer;
      Fer_jh[row * 4 + h] = fer;
      Eer_hj[h * NN + row] = eer;
      Fer_hj[h * NN + row] = fer;
    }
  }
}

// -------- K3: Z1[h] + mask + Esb = f16(exp(s)*rZ2, masked). grid 2048 ------
__global__ __launch_bounds__(256) void k_rowz(
    const float* __restrict__ adj, const float* __restrict__ s,
    const float* __restrict__ Eel, const float* __restrict__ Fel,
    const float* __restrict__ Eer_jh, const float* __restrict__ Fer_jh,
    float* __restrict__ rZ1, _Float16* __restrict__ Esb,
    unsigned long long* __restrict__ maskb) {
  __shared__ float es_row[2048];
  __shared__ float wr[4][5];
  const int row = blockIdx.x;
  const int tid = threadIdx.x;
  const int wq = tid >> 6;
  const int lane = tid & 63;

  float4 e4 = *(const float4*)(Eel + row * 4);
  float4 f4 = *(const float4*)(Fel + row * 4);
  const float eel[4] = {e4.x, e4.y, e4.z, e4.w};
  const float fel[4] = {f4.x, f4.y, f4.z, f4.w};

  float z1[4] = {0.f, 0.f, 0.f, 0.f};
  float z2 = 0.f;

  const float* ap = adj + (size_t)row * NN + wq * 512;
  const float* sp = s + (size_t)row * NN + wq * 512;

#pragma unroll
  for (int it = 0; it < 8; ++it) {
    const int j = it * 64 + lane;
    float a = ap[j];
    float sv = sp[j];
    bool nb = (a != 0.f);
    unsigned long long m = __ballot(nb);
    if (lane == 0) maskb[row * 32 + wq * 8 + it] = m;
    const int jg = wq * 512 + j;
    float es = nb ? __expf(sv) : 0.f;
    es_row[jg] = es;
    z2 += es;
    float4 eer4 = *(const float4*)(Eer_jh + jg * 4);
    float4 fer4 = *(const float4*)(Fer_jh + jg * 4);
    float ev[4] = {eer4.x, eer4.y, eer4.z, eer4.w};
    float fv[4] = {fer4.x, fer4.y, fer4.z, fer4.w};
#pragma unroll
    for (int h = 0; h < 4; ++h) {
      float p = eel[h] * ev[h];
      float q = fel[h] * fv[h];
      float E = fmaxf(p, q);  // == (p>1 ? p : q), exp monotone
      z1[h] += nb ? E : 0.f;
    }
  }

#pragma unroll
  for (int m = 1; m < 64; m <<= 1) {
    z2 += __shfl_xor(z2, m);
#pragma unroll
    for (int h = 0; h < 4; ++h) z1[h] += __shfl_xor(z1[h], m);
  }

  if (lane == 0) {
    wr[wq][0] = z1[0]; wr[wq][1] = z1[1]; wr[wq][2] = z1[2]; wr[wq][3] = z1[3];
    wr[wq][4] = z2;
  }
  __syncthreads();
  if (tid < 4) {
    float sum = wr[0][tid] + wr[1][tid] + wr[2][tid] + wr[3][tid];
    rZ1[row * 4 + tid] = 1.f / sum;
  }
  // second pass: Esb = f16(es * rZ2), 8 j's per thread, 16B store
  const float rz2 = 1.f / (wr[0][4] + wr[1][4] + wr[2][4] + wr[3][4]);
  union { ushort u[8]; float4 f4; } pk;
#pragma unroll
  for (int e = 0; e < 8; ++e) {
    _Float16 hv = (_Float16)(es_row[tid * 8 + e] * rz2);
    union { _Float16 h; ushort u; } cv; cv.h = hv;
    pk.u[e] = cv.u;
  }
  *(float4*)(Esb + (size_t)row * NN + tid * 8) = pk.f4;
}

// -------- K4: coefficient + MFMA contraction. grid 1024 (8 j-chunks) ------
// wave = head h; lane: il = lane&15 (i-row), kg = lane>>4 (k-group)
__global__ __launch_bounds__(256, 8) void k_attn(
    const _Float16* __restrict__ Esb, const unsigned long long* __restrict__ maskb,
    const ushort* __restrict__ gTb,
    const float* __restrict__ Eel, const float* __restrict__ Fel,
    const float* __restrict__ Eer_hj, const float* __restrict__ Fer_hj,
    const float* __restrict__ rZ1,
    _Float16* __restrict__ U, float* __restrict__ Z3p) {
  const int tid = threadIdx.x;
  const int h = tid >> 6;
  const int lane = tid & 63;
  const int il = lane & 15;
  const int kg = lane >> 4;
  const int ib = blockIdx.x >> 3;
  const int jc = blockIdx.x & 7;
  const int i0 = ib * 16;
  const int jb0 = jc * 256;
  const int row = i0 + il;

  const float rz1 = rZ1[row * 4 + h];
  const float eelz = Eel[row * 4 + h] * rz1;
  const float felz = Fel[row * 4 + h] * rz1;

  const unsigned long long* mp = maskb + row * 32 + jc * 4;
  const unsigned long long m0 = mp[0];
  const unsigned long long m1 = mp[1];
  const unsigned long long m2 = mp[2];
  const unsigned long long m3 = mp[3];

  f32x4 acc[4];
#pragma unroll
  for (int nt = 0; nt < 4; ++nt) acc[nt] = (f32x4){0.f, 0.f, 0.f, 0.f};
  float z3 = 0.f;

  const _Float16* ep = Esb + (size_t)row * NN + jb0 + kg * 8;
  const float* eerp = Eer_hj + h * NN + jb0 + kg * 8;
  const float* ferp = Fer_hj + h * NN + jb0 + kg * 8;
  const ushort* bp = gTb + (size_t)(jc * 32 + kg) * 2048 + (h * 64 + il) * 8;

#pragma unroll
  for (int ks = 0; ks < 8; ++ks) {
    const int o = ks * 32;
    unsigned long long w = (ks >> 1) == 0 ? m0
                         : (ks >> 1) == 1 ? m1
                         : (ks >> 1) == 2 ? m2 : m3;
    unsigned byte_ = (unsigned)(w >> ((ks & 1) * 32 + kg * 8)) & 0xffu;

    union { float4 f4; _Float16 hx[8]; } eu;
    eu.f4 = *(const float4*)(ep + o);

    bf16x8 A;
#pragma unroll
    for (int gp = 0; gp < 2; ++gp) {
      float4 ee4 = *(const float4*)(eerp + o + gp * 4);
      float4 fe4 = *(const float4*)(ferp + o + gp * 4);
      float ev[4] = {ee4.x, ee4.y, ee4.z, ee4.w};
      float fv[4] = {fe4.x, fe4.y, fe4.z, fe4.w};
#pragma unroll
      for (int e = 0; e < 4; ++e) {
        const int ei = gp * 4 + e;
        bool nb = (byte_ >> ei) & 1u;
        float p = eelz * ev[e];
        float q = felz * fv[e];
        float E = fmaxf(p, q);
        float tt = nb ? (E + (float)eu.hx[ei]) : 0.f;
        float c = __expf(tt);
        z3 += c;
        A[ei] = (short)f2bf(c);
      }
    }

    const ushort* bks = bp + (size_t)(ks * 4) * 2048;
    acc[0] = __builtin_amdgcn_mfma_f32_16x16x32_bf16(A, *(const bf16x8*)(bks), acc[0], 0, 0, 0);
    acc[1] = __builtin_amdgcn_mfma_f32_16x16x32_bf16(A, *(const bf16x8*)(bks + 128), acc[1], 0, 0, 0);
    acc[2] = __builtin_amdgcn_mfma_f32_16x16x32_bf16(A, *(const bf16x8*)(bks + 256), acc[2], 0, 0, 0);
    acc[3] = __builtin_amdgcn_mfma_f32_16x16x32_bf16(A, *(const bf16x8*)(bks + 384), acc[3], 0, 0, 0);
  }

  z3 += __shfl_xor(z3, 16);
  z3 += __shfl_xor(z3, 32);
  if (lane < 16)
    Z3p[jc * (NN * 4) + (i0 + lane) * 4 + h] = z3;

  _Float16* up = U + (size_t)jc * (NN * 256) + (size_t)i0 * 256 + h * 64 + il;
#pragma unroll
  for (int nt = 0; nt < 4; ++nt)
#pragma unroll
    for (int q = 0; q < 4; ++q)
      up[(size_t)(kg * 4 + q) * 256 + nt * 16] = (_Float16)acc[nt][q];
}

// -------- K5: combine 8 partials, divide by Z3 --------
__global__ __launch_bounds__(256) void k_final(
    const _Float16* __restrict__ U, const float* __restrict__ Z3p,
    float* __restrict__ out) {
  const int i = blockIdx.x;
  const int c = threadIdx.x;
  const int h = c >> 6;
  float u = 0.f, z = 0.f;
#pragma unroll
  for (int p = 0; p < 8; ++p) {
    u += (float)U[(size_t)p * (NN * 256) + (size_t)i * 256 + c];
    z += Z3p[p * (NN * 4) + i * 4 + h];
  }
  out[(size_t)i * 256 + c] = u / z;
}

extern "C" void kernel_launch(void* const* d_in, const int* in_sizes, int n_in,
                              void* d_out, int out_size, void* d_ws, size_t ws_size,
                              hipStream_t stream) {
  const float* hin = (const float*)d_in[0];
  const float* adj = (const float*)d_in[1];
  const float* s = (const float*)d_in[2];
  const float* W = (const float*)d_in[3];
  const float* aw = (const float*)d_in[4];
  float* out = (float*)d_out;

  // Workspace layout (f32 slots) — audited, non-overlapping:
  //  Eel     [      0,    8192)
  //  Fel     [   8192,   16384)
  //  Eer_jh  [  16384,   24576)
  //  Fer_jh  [  24576,   32768)
  //  Eer_hj  [  32768,   40960)
  //  Fer_hj  [  40960,   49152)
  //  rZ1     [  49152,   57344)
  //  Z3p     [  57344,  122880)   8 * 8192
  //  maskb   [ 122880,  253952)   65536 u64 = 131072 slots (byte 491520 % 8 == 0)
  //  wthi    [ 253952,  319488)   131072 ushort
  //  wtlo    [ 319488,  385024)   131072 ushort
  //  gTb     [ 385024,  647168)   524288 ushort
  //  Esb     [ 647168, 2744320)   2048*2048 f16 = 2097152 slots
  //  U       [2744320, 4841472)   8*2048*256 f16 = 2097152 slots
  float* ws = (float*)d_ws;
  float* Eel    = ws;
  float* Fel    = ws + 8192;
  float* Eer_jh = ws + 16384;
  float* Fer_jh = ws + 24576;
  float* Eer_hj = ws + 32768;
  float* Fer_hj = ws + 40960;
  float* rZ1    = ws + 49152;
  float* Z3p    = ws + 57344;
  unsigned long long* maskb = (unsigned long long*)(ws + 122880);
  ushort* wthi  = (ushort*)(ws + 253952);
  ushort* wtlo  = (ushort*)(ws + 319488);
  ushort* gTb   = (ushort*)(ws + 385024);
  _Float16* Esb = (_Float16*)(ws + 647168);
  _Float16* U   = (_Float16*)(ws + 2744320);

  k_wprep<<<32, 256, 0, stream>>>(W, wthi, wtlo);
  k_gemm<<<128, 256, 0, stream>>>(hin, wthi, wtlo, aw, gTb, Eel, Fel, Eer_jh, Fer_jh, Eer_hj, Fer_hj);
  k_rowz<<<2048, 256, 0, stream>>>(adj, s, Eel, Fel, Eer_jh, Fer_jh, rZ1, Esb, maskb);
  k_attn<<<1024, 256, 0, stream>>>(Esb, maskb, gTb, Eel, Fel, Eer_hj, Fer_hj, rZ1, U, Z3p);
  k_final<<<2048, 256, 0, stream>>>(U, Z3p, out);
}

// Round 9
// 73.790 us; speedup vs baseline: 5.7268x; 1.2534x over previous
//
#include <hip/hip_runtime.h>

#define NN 2048
#define KK 512

typedef __attribute__((ext_vector_type(8))) short bf16x8;
typedef __attribute__((ext_vector_type(4))) float f32x4;

__device__ inline ushort f2bf(float x) {  // RNE f32->bf16
  union { float f; unsigned u; } v; v.f = x;
  unsigned r = v.u + 0x7fffu + ((v.u >> 16) & 1u);
  return (ushort)(r >> 16);
}

// -------- K0: W -> WT_hi/WT_lo (bf16 split, [n][k] layout). grid 32 --------
__global__ __launch_bounds__(256) void k_wprep(
    const float* __restrict__ W, ushort* __restrict__ wthi,
    ushort* __restrict__ wtlo) {
  __shared__ float ts[64][65];
  const int t = threadIdx.x;
  const int kb = (blockIdx.x >> 2) * 64;
  const int nb = (blockIdx.x & 3) * 64;
  const int r = t >> 6, c = t & 63;
#pragma unroll
  for (int p = 0; p < 16; ++p)
    ts[p * 4 + r][c] = W[(size_t)(kb + p * 4 + r) * 256 + nb + c];
  __syncthreads();
#pragma unroll
  for (int p = 0; p < 16; ++p) {
    int n = p * 4 + r;
    int k = c;
    float v = ts[k][n];
    union { float f; unsigned u; } q; q.f = v;
    ushort hi = (ushort)(q.u >> 16);
    union { float f; unsigned u; } hf; hf.u = q.u & 0xffff0000u;
    ushort lo = f2bf(v - hf.f);
    size_t off = (size_t)(nb + n) * KK + kb + k;
    wthi[off] = hi;
    wtlo[off] = lo;
  }
}

// -------- K1: g = h@W via split-bf16 MFMA; writes gTb + exp tables ---------
// grid 128 (16 rows each), block 256 (wave = head). Proven R6-R8.
__global__ __launch_bounds__(256) void k_gemm(
    const float* __restrict__ hin, const ushort* __restrict__ wthi,
    const ushort* __restrict__ wtlo, const float* __restrict__ aw,
    ushort* __restrict__ gTb,
    float* __restrict__ Eel, float* __restrict__ Fel,
    float* __restrict__ Eer_jh, float* __restrict__ Fer_jh,
    float* __restrict__ Eer_hj, float* __restrict__ Fer_hj) {
  __shared__ float hs[16][516];
  const int tid = threadIdx.x;
  const int i0 = blockIdx.x * 16;
#pragma unroll
  for (int p = 0; p < 8; ++p) {
    int g4 = tid + p * 256;
    int row = g4 >> 7, col = (g4 & 127) << 2;
    *(float4*)&hs[row][col] = *(const float4*)(hin + (size_t)(i0 + row) * KK + col);
  }
  __syncthreads();

  const int h = tid >> 6;
  const int lane = tid & 63;
  const int il = lane & 15;
  const int kg = lane >> 4;

  f32x4 acc[4];
#pragma unroll
  for (int nt = 0; nt < 4; ++nt) acc[nt] = (f32x4){0.f, 0.f, 0.f, 0.f};

  const ushort* bh_base = wthi + (size_t)(h * 64 + il) * KK;
  const ushort* bl_base = wtlo + (size_t)(h * 64 + il) * KK;

#pragma unroll 4
  for (int ks = 0; ks < 16; ++ks) {
    const int ko = ks * 32 + kg * 8;
    float4 a01 = *(const float4*)&hs[il][ko];
    float4 a23 = *(const float4*)&hs[il][ko + 4];
    float av[8] = {a01.x, a01.y, a01.z, a01.w, a23.x, a23.y, a23.z, a23.w};
    union { unsigned u[4]; bf16x8 v; } Ah, Al;
#pragma unroll
    for (int p = 0; p < 4; ++p) {
      union { float f; unsigned u; } u0, u1;
      u0.f = av[2 * p]; u1.f = av[2 * p + 1];
      Ah.u[p] = (u0.u >> 16) | (u1.u & 0xffff0000u);
      union { float f; unsigned u; } h0, h1;
      h0.u = u0.u & 0xffff0000u;
      h1.u = u1.u & 0xffff0000u;
      union { float f; unsigned u; } r0, r1;
      r0.f = av[2 * p] - h0.f;
      r1.f = av[2 * p + 1] - h1.f;
      Al.u[p] = (r0.u >> 16) | (r1.u & 0xffff0000u);
    }
#pragma unroll
    for (int nt = 0; nt < 4; ++nt) {
      bf16x8 Bh = *(const bf16x8*)(bh_base + nt * 16 * KK + ko);
      bf16x8 Bl = *(const bf16x8*)(bl_base + nt * 16 * KK + ko);
      acc[nt] = __builtin_amdgcn_mfma_f32_16x16x32_bf16(Ah.v, Bh, acc[nt], 0, 0, 0);
      acc[nt] = __builtin_amdgcn_mfma_f32_16x16x32_bf16(Al.v, Bh, acc[nt], 0, 0, 0);
      acc[nt] = __builtin_amdgcn_mfma_f32_16x16x32_bf16(Ah.v, Bl, acc[nt], 0, 0, 0);
    }
  }

  // gTb write: layout [j/8][f][8] bf16
  const int jb = (i0 >> 3) + (kg >> 1);
  const int halfoff = (kg & 1) * 4;
#pragma unroll
  for (int nt = 0; nt < 4; ++nt) {
    const int f = h * 64 + nt * 16 + il;
    unsigned w0 = (unsigned)f2bf(acc[nt][0]) | ((unsigned)f2bf(acc[nt][1]) << 16);
    unsigned w1 = (unsigned)f2bf(acc[nt][2]) | ((unsigned)f2bf(acc[nt][3]) << 16);
    uint2 pk = make_uint2(w0, w1);
    *(uint2*)(gTb + (size_t)jb * 2048 + f * 8 + halfoff) = pk;
  }

  // el/er epilogue -> exp tables directly
  float ela[4] = {0.f, 0.f, 0.f, 0.f}, era[4] = {0.f, 0.f, 0.f, 0.f};
#pragma unroll
  for (int nt = 0; nt < 4; ++nt) {
    float as = aw[nt * 16 + il];
    float ad = aw[64 + nt * 16 + il];
#pragma unroll
    for (int q = 0; q < 4; ++q) {
      ela[q] += acc[nt][q] * as;
      era[q] += acc[nt][q] * ad;
    }
  }
#pragma unroll
  for (int m = 1; m < 16; m <<= 1) {
#pragma unroll
    for (int q = 0; q < 4; ++q) {
      ela[q] += __shfl_xor(ela[q], m);
      era[q] += __shfl_xor(era[q], m);
    }
  }
  if (il == 0) {
#pragma unroll
    for (int q = 0; q < 4; ++q) {
      const int row = i0 + kg * 4 + q;
      float eel = __expf(ela[q]);
      float fel = __expf(0.2f * ela[q]);
      float eer = __expf(era[q]);
      float fer = __expf(0.2f * era[q]);
      Eel[row * 4 + h] = eel;
      Fel[row * 4 + h] = fel;
      Eer_jh[row * 4 + h] = eer;
      Fer_jh[row * 4 + h] = fer;
      Eer_hj[h * NN + row] = eer;
      Fer_hj[h * NN + row] = fer;
    }
  }
}

// -------- K3: Z1[h], Z2 + adjacency bitmask. grid 2048 (block = row) -------
// R6-proven version (+rZ2 output).
__global__ __launch_bounds__(256) void k_rowz(
    const float* __restrict__ adj, const float* __restrict__ s,
    const float* __restrict__ Eel, const float* __restrict__ Fel,
    const float* __restrict__ Eer_jh, const float* __restrict__ Fer_jh,
    float* __restrict__ rZ1, float* __restrict__ rZ2,
    unsigned long long* __restrict__ maskb) {
  const int row = blockIdx.x;
  const int tid = threadIdx.x;
  const int wq = tid >> 6;
  const int lane = tid & 63;

  float4 e4 = *(const float4*)(Eel + row * 4);
  float4 f4 = *(const float4*)(Fel + row * 4);
  const float eel[4] = {e4.x, e4.y, e4.z, e4.w};
  const float fel[4] = {f4.x, f4.y, f4.z, f4.w};

  float z1[4] = {0.f, 0.f, 0.f, 0.f};
  float z2 = 0.f;

  const float* ap = adj + (size_t)row * NN + wq * 512;
  const float* sp = s + (size_t)row * NN + wq * 512;

#pragma unroll
  for (int it = 0; it < 8; ++it) {
    const int j = it * 64 + lane;
    float a = ap[j];
    float sv = sp[j];
    bool nb = (a != 0.f);
    unsigned long long m = __ballot(nb);
    if (lane == 0) maskb[row * 32 + wq * 8 + it] = m;
    const int jg = wq * 512 + j;
    float4 eer4 = *(const float4*)(Eer_jh + jg * 4);
    float4 fer4 = *(const float4*)(Fer_jh + jg * 4);
    z2 += nb ? __expf(sv) : 0.f;
    float ev[4] = {eer4.x, eer4.y, eer4.z, eer4.w};
    float fv[4] = {fer4.x, fer4.y, fer4.z, fer4.w};
#pragma unroll
    for (int h = 0; h < 4; ++h) {
      float p = eel[h] * ev[h];
      float q = fel[h] * fv[h];
      float E = fmaxf(p, q);  // == (p>1 ? p : q), exp monotone
      z1[h] += nb ? E : 0.f;
    }
  }

#pragma unroll
  for (int m = 1; m < 64; m <<= 1) {
    z2 += __shfl_xor(z2, m);
#pragma unroll
    for (int h = 0; h < 4; ++h) z1[h] += __shfl_xor(z1[h], m);
  }

  __shared__ float wr[4][5];
  if (lane == 0) {
    wr[wq][0] = z1[0]; wr[wq][1] = z1[1]; wr[wq][2] = z1[2]; wr[wq][3] = z1[3];
    wr[wq][4] = z2;
  }
  __syncthreads();
  if (tid < 5) {
    float sum = wr[0][tid] + wr[1][tid] + wr[2][tid] + wr[3][tid];
    if (tid < 4) rZ1[row * 4 + tid] = 1.f / sum;
    else rZ2[row] = 1.f / sum;
  }
}

// -------- K4: LDS-staged coefficient + MFMA contraction. grid 2048 ---------
// (ib = bx>>4, jc = bx&15). wave = head h; lane: il (i-row), kg (k-group).
__global__ __launch_bounds__(256, 8) void k_attn(
    const float* __restrict__ s, const unsigned long long* __restrict__ maskb,
    const ushort* __restrict__ gTb,
    const float* __restrict__ Eel, const float* __restrict__ Fel,
    const float* __restrict__ Eer_hj, const float* __restrict__ Fer_hj,
    const float* __restrict__ rZ1, const float* __restrict__ rZ2,
    _Float16* __restrict__ U, float* __restrict__ Z3p) {
  __shared__ float esb_s[16][132];  // exp(s)*rZ2, masked
  __shared__ float eer_s[4][132];
  __shared__ float fer_s[4][132];

  const int tid = threadIdx.x;
  const int h = tid >> 6;
  const int lane = tid & 63;
  const int il = lane & 15;
  const int kg = lane >> 4;
  const int ib = blockIdx.x >> 4;
  const int jc = blockIdx.x & 15;
  const int i0 = ib * 16;
  const int jb0 = jc * 128;
  const int row = i0 + il;

  // ---- stage: esb (exp(s)*rz2 masked), eer, fer ----
  {
    const int r = tid >> 4;            // 0..15
    const int c8 = (tid & 15) * 8;     // 0..120
    const int rowr = i0 + r;
    const float rz2r = rZ2[rowr];
    unsigned long long mw = maskb[rowr * 32 + jc * 2 + (c8 >> 6)];
    unsigned byte_ = (unsigned)(mw >> (c8 & 63)) & 0xffu;
    float4 sa = *(const float4*)(s + (size_t)rowr * NN + jb0 + c8);
    float4 sb = *(const float4*)(s + (size_t)rowr * NN + jb0 + c8 + 4);
    float sv[8] = {sa.x, sa.y, sa.z, sa.w, sb.x, sb.y, sb.z, sb.w};
#pragma unroll
    for (int e = 0; e < 8; ++e)
      esb_s[r][c8 + e] = ((byte_ >> e) & 1u) ? __expf(sv[e]) * rz2r : 0.f;
  }
  {
    const int hh = (tid & 127) >> 5;
    const int c4 = (tid & 31) * 4;
    const float* src = (tid < 128) ? Eer_hj : Fer_hj;
    float4 v = *(const float4*)(src + hh * NN + jb0 + c4);
    float* dst = (tid < 128) ? &eer_s[hh][c4] : &fer_s[hh][c4];
    dst[0] = v.x; dst[1] = v.y; dst[2] = v.z; dst[3] = v.w;
  }
  __syncthreads();

  const float rz1 = rZ1[row * 4 + h];
  const float eelz = Eel[row * 4 + h] * rz1;
  const float felz = Fel[row * 4 + h] * rz1;

  const unsigned long long* mp = maskb + row * 32 + jc * 2;
  const unsigned long long m0 = mp[0];
  const unsigned long long m1 = mp[1];

  f32x4 acc[4];
#pragma unroll
  for (int nt = 0; nt < 4; ++nt) acc[nt] = (f32x4){0.f, 0.f, 0.f, 0.f};
  float z3 = 0.f;

  const ushort* bp = gTb + (size_t)(jc * 16 + kg) * 2048 + (h * 64 + il) * 8;

#pragma unroll
  for (int ks = 0; ks < 4; ++ks) {
    // B loads first (independent; overlap with coefficient VALU)
    const ushort* bks = bp + (size_t)(ks * 4) * 2048;
    bf16x8 B0 = *(const bf16x8*)(bks);
    bf16x8 B1 = *(const bf16x8*)(bks + 128);
    bf16x8 B2 = *(const bf16x8*)(bks + 256);
    bf16x8 B3 = *(const bf16x8*)(bks + 384);

    unsigned long long w = (ks & 2) ? m1 : m0;
    unsigned byte_ = (unsigned)(w >> ((ks & 1) * 32 + kg * 8)) & 0xffu;
    const int jl = ks * 32 + kg * 8;

    bf16x8 A;
#pragma unroll
    for (int e = 0; e < 8; ++e) {
      bool nb = (byte_ >> e) & 1u;
      float p = eelz * eer_s[h][jl + e];
      float q = felz * fer_s[h][jl + e];
      float tt = nb ? (fmaxf(p, q) + esb_s[il][jl + e]) : 0.f;
      float c = __expf(tt);
      z3 += c;
      A[e] = (short)f2bf(c);
    }

    acc[0] = __builtin_amdgcn_mfma_f32_16x16x32_bf16(A, B0, acc[0], 0, 0, 0);
    acc[1] = __builtin_amdgcn_mfma_f32_16x16x32_bf16(A, B1, acc[1], 0, 0, 0);
    acc[2] = __builtin_amdgcn_mfma_f32_16x16x32_bf16(A, B2, acc[2], 0, 0, 0);
    acc[3] = __builtin_amdgcn_mfma_f32_16x16x32_bf16(A, B3, acc[3], 0, 0, 0);
  }

  z3 += __shfl_xor(z3, 16);
  z3 += __shfl_xor(z3, 32);
  if (lane < 16)
    Z3p[jc * (NN * 4) + (i0 + lane) * 4 + h] = z3;

  _Float16* up = U + (size_t)jc * (NN * 256) + (size_t)i0 * 256 + h * 64 + il;
#pragma unroll
  for (int nt = 0; nt < 4; ++nt)
#pragma unroll
    for (int q = 0; q < 4; ++q)
      up[(size_t)(kg * 4 + q) * 256 + nt * 16] = (_Float16)acc[nt][q];
}

// -------- K5: combine 16 partials, divide by Z3 --------
__global__ __launch_bounds__(256) void k_final(
    const _Float16* __restrict__ U, const float* __restrict__ Z3p,
    float* __restrict__ out) {
  const int i = blockIdx.x;
  const int c = threadIdx.x;
  const int h = c >> 6;
  float u = 0.f, z = 0.f;
#pragma unroll
  for (int p = 0; p < 16; ++p) {
    u += (float)U[(size_t)p * (NN * 256) + (size_t)i * 256 + c];
    z += Z3p[p * (NN * 4) + i * 4 + h];
  }
  out[(size_t)i * 256 + c] = u / z;
}

extern "C" void kernel_launch(void* const* d_in, const int* in_sizes, int n_in,
                              void* d_out, int out_size, void* d_ws, size_t ws_size,
                              hipStream_t stream) {
  const float* hin = (const float*)d_in[0];
  const float* adj = (const float*)d_in[1];
  const float* s = (const float*)d_in[2];
  const float* W = (const float*)d_in[3];
  const float* aw = (const float*)d_in[4];
  float* out = (float*)d_out;

  // Workspace layout (f32 slots) — audited, non-overlapping (19.6 MB, R4-proven size):
  //  Eel     [      0,    8192)
  //  Fel     [   8192,   16384)
  //  Eer_jh  [  16384,   24576)
  //  Fer_jh  [  24576,   32768)
  //  Eer_hj  [  32768,   40960)
  //  Fer_hj  [  40960,   49152)
  //  rZ1     [  49152,   57344)
  //  rZ2     [  57344,   59392)
  //  Z3p     [  59392,  190464)   16 * 8192
  //  maskb   [ 190464,  321536)   65536 u64 (byte 761856 % 8 == 0)
  //  wthi    [ 321536,  387072)   131072 ushort
  //  wtlo    [ 387072,  452608)   131072 ushort
  //  gTb     [ 452608,  714752)   524288 ushort
  //  U       [ 714752, 4909056)   16*2048*256 f16
  float* ws = (float*)d_ws;
  float* Eel    = ws;
  float* Fel    = ws + 8192;
  float* Eer_jh = ws + 16384;
  float* Fer_jh = ws + 24576;
  float* Eer_hj = ws + 32768;
  float* Fer_hj = ws + 40960;
  float* rZ1    = ws + 49152;
  float* rZ2    = ws + 57344;
  float* Z3p    = ws + 59392;
  unsigned long long* maskb = (unsigned long long*)(ws + 190464);
  ushort* wthi  = (ushort*)(ws + 321536);
  ushort* wtlo  = (ushort*)(ws + 387072);
  ushort* gTb   = (ushort*)(ws + 452608);
  _Float16* U   = (_Float16*)(ws + 714752);

  k_wprep<<<32, 256, 0, stream>>>(W, wthi, wtlo);
  k_gemm<<<128, 256, 0, stream>>>(hin, wthi, wtlo, aw, gTb, Eel, Fel, Eer_jh, Fer_jh, Eer_hj, Fer_hj);
  k_rowz<<<2048, 256, 0, stream>>>(adj, s, Eel, Fel, Eer_jh, Fer_jh, rZ1, rZ2, maskb);
  k_attn<<<2048, 256, 0, stream>>>(s, maskb, gTb, Eel, Fel, Eer_hj, Fer_hj, rZ1, rZ2, U, Z3p);
  k_final<<<2048, 256, 0, stream>>>(U, Z3p, out);
}